// Round 3
// baseline (125.178 us; speedup 1.0000x reference)
//
#include <hip/hip_runtime.h>
#include <hip/hip_bf16.h>
#include <math.h>

namespace {
typedef __attribute__((ext_vector_type(8)))  short  short8;   // 8 bf16 = 4 VGPR (MFMA A/B frag)
typedef __attribute__((ext_vector_type(4)))  float  floatx4;  // MFMA C/D frag
typedef _Float16 f16;
typedef __attribute__((ext_vector_type(4)))  _Float16 half4;
typedef __attribute__((ext_vector_type(8)))  _Float16 half8;

constexpr int Bc = 16;    // batch
constexpr int DC = 16;    // deep channels
constexpr int ND = 1024;  // deep length
constexpr int C  = 64;    // c_in
constexpr int N  = 4096;  // sequence
constexpr int CO = 128;   // c_out
constexpr int KW = 7;
constexpr int F  = C * KW;     // 448
constexpr int LT = 32;         // l-tile in k2
constexpr int PLD = F + 8;     // 456 bf16/row (912 B, 16B-aligned rows)

__device__ inline unsigned short f2bf(float f) {
    __hip_bfloat16 h = __float2bfloat16(f);      // RNE
    return __builtin_bit_cast(unsigned short, h);
}
__device__ inline float rcpf(float x) { return __builtin_amdgcn_rcpf(x); }

// K1 blocks 0..1023: one per (b,c).
//   conv commutes with linear interp: V[t] = sum_d cw[d]*deep[d][t] (LDS),
//   then y(4t+r) = lerp of V[t-1],V[t],V[t+1] with fixed weights. mean/var, xs=fp16.
// K1 blocks 1024..1079: convert fc_w fp32 -> bf16 into ws (needed by k2).
__global__ __launch_bounds__(256)
void k1(const float* __restrict__ deep, const float* __restrict__ conv_w,
        const float* __restrict__ conv_b, const float* __restrict__ fcw,
        f16* __restrict__ xs, unsigned short* __restrict__ wb)
{
    if (blockIdx.x >= Bc * C) {                      // fc_w -> bf16, 56 blocks
        const int i = ((blockIdx.x - Bc * C) * 256 + threadIdx.x) * 4;  // < 57344
        const float4 v = *(const float4*)(fcw + i);
        ushort4 o;
        o.x = f2bf(v.x); o.y = f2bf(v.y); o.z = f2bf(v.z); o.w = f2bf(v.w);
        *(ushort4*)(wb + i) = o;
        return;
    }
    const int b = blockIdx.x >> 6;
    const int c = blockIdx.x & 63;
    const int tid = threadIdx.x;
    __shared__ float V[ND];
    __shared__ float r1[256], r2[256];

    float cw[DC];
#pragma unroll
    for (int d = 0; d < DC; ++d) cw[d] = conv_w[c * DC + d];   // uniform -> s_load
    const float cb = conv_b[c];
    const float* dp = deep + b * DC * ND;

#pragma unroll
    for (int p = 0; p < 4; ++p) {
        const int t = tid + 256 * p;
        float a = 0.f;
#pragma unroll
        for (int d = 0; d < DC; ++d) a = fmaf(dp[d * ND + t], cw[d], a);
        V[t] = a;
    }
    __syncthreads();

    float s1 = 0.f, s2 = 0.f;
#pragma unroll
    for (int it = 0; it < 4; ++it) {
        const int g = tid + 256 * it;
        const float vm = V[g == 0 ? 0 : g - 1];
        const float v0 = V[g];
        const float vp = V[g == ND - 1 ? ND - 1 : g + 1];
        const float y0 = fmaf(0.375f, vm, fmaf(0.625f, v0, cb));
        const float y1 = fmaf(0.125f, vm, fmaf(0.875f, v0, cb));
        const float y2 = fmaf(0.125f, vp, fmaf(0.875f, v0, cb));
        const float y3 = fmaf(0.375f, vp, fmaf(0.625f, v0, cb));
        s1 += (y0 + y1) + (y2 + y3);
        s2 = fmaf(y0, y0, s2); s2 = fmaf(y1, y1, s2);
        s2 = fmaf(y2, y2, s2); s2 = fmaf(y3, y3, s2);
    }
    r1[tid] = s1; r2[tid] = s2;
    __syncthreads();
    for (int off = 128; off > 0; off >>= 1) {
        if (tid < off) { r1[tid] += r1[tid + off]; r2[tid] += r2[tid + off]; }
        __syncthreads();
    }
    const float mean = r1[0] * (1.f / N);
    const float var  = (r2[0] - (float)N * mean * mean) * (1.f / (N - 1));  // ddof=1
    const float sc   = 0.5f / (var + 1e-9f);                                // GAMA/(var+EPS)

    f16* xsp = xs + (b * C + c) * N;
#pragma unroll
    for (int it = 0; it < 4; ++it) {
        const int g = tid + 256 * it;
        const float vm = V[g == 0 ? 0 : g - 1];
        const float v0 = V[g];
        const float vp = V[g == ND - 1 ? ND - 1 : g + 1];
        half4 h;
        h.x = (f16)((fmaf(0.375f, vm, fmaf(0.625f, v0, cb)) - mean) * sc);
        h.y = (f16)((fmaf(0.125f, vm, fmaf(0.875f, v0, cb)) - mean) * sc);
        h.z = (f16)((fmaf(0.125f, vp, fmaf(0.875f, v0, cb)) - mean) * sc);
        h.w = (f16)((fmaf(0.375f, vp, fmaf(0.625f, v0, cb)) - mean) * sc);
        *(half4*)(xsp + 4 * g) = h;
    }
}

// K2: one block per (b, 32-l tile).
// Phase 1: thread owns (c = tid&63, 8 consecutive l). All 56 taps live in a
//   14-wide window [base-3, base+10] -> 3x half8 + 4x float4 vector loads,
//   compute from registers (compile-time indexed). Edge reflect on a
//   wave-uniform branch (seg = tid>>6 is the wave id).
//   phi[l][c*7+k] = bf16( alpha * sech^2|xs_p - xs_center| * x_p )  (LDS)
// Phase 2: out[o,l] = sum_f w[o,f]*phi[l,f] via mfma_f32_16x16x32_bf16;
//   wave w owns o-stripe [32w,32w+32): 2x2 D-tiles of 16x16, K=448 in 14 steps.
__global__ __launch_bounds__(256)
void k2(const f16* __restrict__ xs, const float* __restrict__ x,
        const unsigned short* __restrict__ wb, float* __restrict__ out)
{
    __shared__ __align__(16) unsigned short phi[LT * PLD];
    const int b   = blockIdx.y;
    const int l0  = blockIdx.x * LT;
    const int tid = threadIdx.x;

    // ---- phase 1 ----
    {
        const int c    = tid & 63;
        const int seg  = tid >> 6;          // wave id, 0..3
        const int base = l0 + seg * 8;      // multiple of 8
        const f16*   xsr = xs + (b * C + c) * N;
        const float* xr  = x  + (b * C + c) * N;

        float vs[14], xv[14];               // window positions base-3 .. base+10
        const bool edge = (blockIdx.x == 0 && seg == 0) ||
                          (blockIdx.x == (N / LT - 1) && seg == 3);
        if (!edge) {
            const half8 a0 = *(const half8*)(xsr + base - 8);
            const half8 a1 = *(const half8*)(xsr + base);
            const half8 a2 = *(const half8*)(xsr + base + 8);
            const float4 x0 = *(const float4*)(xr + base - 4);
            const float4 x1 = *(const float4*)(xr + base);
            const float4 x2 = *(const float4*)(xr + base + 4);
            const float4 x3 = *(const float4*)(xr + base + 8);
            const float xf[16] = {x0.x, x0.y, x0.z, x0.w, x1.x, x1.y, x1.z, x1.w,
                                  x2.x, x2.y, x2.z, x2.w, x3.x, x3.y, x3.z, x3.w};
#pragma unroll
            for (int i = 0; i < 14; ++i) {
                const int j = 5 + i;        // index into a0|a1|a2 (compile-time)
                const f16 v = (j < 8) ? a0[j] : ((j < 16) ? a1[j - 8] : a2[j - 16]);
                vs[i] = (float)v;
                xv[i] = xf[1 + i];
            }
        } else {
#pragma unroll
            for (int i = 0; i < 14; ++i) {
                int p = base - 3 + i;
                p = (p < 0) ? -p : ((p >= N) ? (2 * N - 2 - p) : p);   // reflect
                vs[i] = (float)xsr[p];
                xv[i] = xr[p];
            }
        }

        unsigned short* pcol = phi + c * KW;
#pragma unroll
        for (int li = 0; li < 8; ++li) {
            const float cen = vs[li + 3];
            float u[KW];
            float s = 0.25f;                 // tap k=3: d=0 -> loss/4 = 1/4 exactly
            u[3] = 0.25f;
#pragma unroll
            for (int k = 0; k < KW; ++k) {
                if (k == 3) continue;
                const float d = fabsf(vs[li + k] - cen);
                const float e = __expf(-2.f * d);   // 1-tanh^2 = 4e^{-2d}/(1+e^{-2d})^2
                const float t = 1.f + e;
                const float uk = e * rcpf(t * t);   // = loss/4
                u[k] = uk;
                s += uk;
            }
            const float al = rcpf(s);               // 4s = sum(loss); al*u = loss/sum
            unsigned short* pr = pcol + (seg * 8 + li) * PLD;
#pragma unroll
            for (int k = 0; k < KW; ++k) pr[k] = f2bf(u[k] * al * xv[li + k]);
        }
    }
    __syncthreads();

    // ---- phase 2 (MFMA) ----
    const int wv   = tid >> 6;
    const int lane = tid & 63;
    const int quad = lane >> 4;     // k-offset = quad*8
    const int rr   = lane & 15;     // free index within tile
    const int o0   = wv * 32;

    floatx4 acc00 = {0.f, 0.f, 0.f, 0.f}, acc01 = acc00, acc10 = acc00, acc11 = acc00;
    const unsigned short* wrow0 = wb + (o0 + rr) * F + quad * 8;        // A tile 0
    const unsigned short* wrow1 = wrow0 + 16 * F;                       // A tile 1
    const unsigned short* prow0 = phi + rr * PLD + quad * 8;            // B tile 0
    const unsigned short* prow1 = prow0 + 16 * PLD;                     // B tile 1

    for (int s = 0; s < F / 32; ++s) {              // 14 K-steps of 32
        const int f0 = 32 * s;
        const short8 a0 = *(const short8*)(wrow0 + f0);
        const short8 a1 = *(const short8*)(wrow1 + f0);
        const short8 b0 = *(const short8*)(prow0 + f0);
        const short8 b1 = *(const short8*)(prow1 + f0);
        acc00 = __builtin_amdgcn_mfma_f32_16x16x32_bf16(a0, b0, acc00, 0, 0, 0);
        acc01 = __builtin_amdgcn_mfma_f32_16x16x32_bf16(a0, b1, acc01, 0, 0, 0);
        acc10 = __builtin_amdgcn_mfma_f32_16x16x32_bf16(a1, b0, acc10, 0, 0, 0);
        acc11 = __builtin_amdgcn_mfma_f32_16x16x32_bf16(a1, b1, acc11, 0, 0, 0);
    }

    // C/D layout (m89-verified): col = lane&15 (=l within tile), row = quad*4 + reg
    float* ob = out + (b * CO) * N + l0;
#pragma unroll
    for (int i = 0; i < 4; ++i) {
        const int om = quad * 4 + i;
        ob[(o0 + om) * N      + rr     ] = acc00[i];
        ob[(o0 + om) * N      + 16 + rr] = acc01[i];
        ob[(o0 + 16 + om) * N + rr     ] = acc10[i];
        ob[(o0 + 16 + om) * N + 16 + rr] = acc11[i];
    }
}
} // namespace

extern "C" void kernel_launch(void* const* d_in, const int* in_sizes, int n_in,
                              void* d_out, int out_size, void* d_ws, size_t ws_size,
                              hipStream_t stream)
{
    const float* deep   = (const float*)d_in[0];
    const float* x      = (const float*)d_in[1];
    const float* conv_w = (const float*)d_in[2];
    const float* conv_b = (const float*)d_in[3];
    const float* fc_w   = (const float*)d_in[4];
    float* out = (float*)d_out;

    f16* xs = (f16*)d_ws;                                              // 8 MiB
    unsigned short* wb = (unsigned short*)((char*)d_ws + (8u << 20));  // 112 KiB bf16 fc_w

    hipLaunchKernelGGL(k1, dim3(Bc * C + 56), dim3(256), 0, stream,
                       deep, conv_w, conv_b, fc_w, xs, wb);
    hipLaunchKernelGGL(k2, dim3(N / LT, Bc), dim3(256), 0, stream,
                       xs, x, wb, out);
}